// Round 5
// baseline (2808.451 us; speedup 1.0000x reference)
//
#include <hip/hip_runtime.h>
#include <hip/hip_bf16.h>

#define BDIM 2
#define SDIM 4096
#define EDIM 2048
#define TOK (BDIM * SDIM)       // 8192
#define QK_SCALE 0.08838834764831845f  // 128^-0.5

typedef short bf16x8 __attribute__((ext_vector_type(8)));
typedef float f32x4 __attribute__((ext_vector_type(4)));

__device__ __forceinline__ unsigned short f2bf(float f) {
    unsigned u = __float_as_uint(f);
    u += 0x7FFF + ((u >> 16) & 1);          // RNE; inputs finite
    return (unsigned short)(u >> 16);
}

// fp32x8 -> bf16 hi + bf16 lo (residual), for near-fp32 MFMA via 3-term split
__device__ __forceinline__ void cvt_split8(const float4 a, const float4 b,
                                           bf16x8& hi, bf16x8& lo) {
    float f[8] = {a.x, a.y, a.z, a.w, b.x, b.y, b.z, b.w};
#pragma unroll
    for (int i = 0; i < 8; ++i) {
        const unsigned short h = f2bf(f[i]);
        hi[i] = (short)h;
        const float hf = __uint_as_float(((unsigned)h) << 16);
        lo[i] = (short)f2bf(f[i] - hf);
    }
}

// async 16B global -> LDS; per-thread dst of form (wave-uniform base + lane*16)
__device__ __forceinline__ void cp16(const void* g, void* l) {
    __builtin_amdgcn_global_load_lds(
        (const __attribute__((address_space(1))) unsigned int*)g,
        (__attribute__((address_space(3))) unsigned int*)l, 16, 0, 0);
}

// LDS anti-bank-conflict involution on 64B rows: XOR row bits[3:1] (byte bits
// 9:7) into byte bits[6:4]. 16B-granularity-preserving, self-inverse.
// (Proven in round 4: SQ_LDS_BANK_CONFLICT -> 0, results bit-correct.)
__device__ __forceinline__ int swz(int L) { return L ^ (((L >> 7) & 7) << 4); }

// ---- one-time fp32 -> bf16 hi/lo split (hoisted out of the GEMMs) ----
__global__ __launch_bounds__(256) void split_kernel(
    const float* __restrict__ x,
    unsigned short* __restrict__ xh, unsigned short* __restrict__ xl) {
    const long i = ((long)blockIdx.x * 256 + threadIdx.x) * 8;
    const float4 f0 = *(const float4*)(x + i);
    const float4 f1 = *(const float4*)(x + i + 4);
    bf16x8 hi, lo;
    cvt_split8(f0, f1, hi, lo);
    *(bf16x8*)(xh + i) = hi;
    *(bf16x8*)(xl + i) = lo;
}

// ====== MFMA GEMM, round-2 rhythm + counted-vmcnt ring-3 pipeline ======
// C[m,n] = sum_seg A_seg[m,k] * B_seg[n,k]   (B^T form)
// Tile 128x256, 512 threads = 8 waves (2M x 4N), per-wave C = 64x64.
// K stream = slots of K=32 (concatenated over nseg segments, per-segment
// A/B base pointers: hi/lo split products are plain segments).
// LDS ring of 3 slots (24KB each, 72KB total -> 2 blocks/CU): while computing
// slot sl, stage slot sl+2 into buf (sl+2)%3 (last read by slot sl-1, whose
// ds_reads completed before its end barrier -> WAR-safe).
// Counted s_waitcnt vmcnt(6) (= loads of slots sl+1, sl+2) before the open
// barrier guarantees slot sl's 3 loads landed WITHOUT draining the pipe.
// Tail: vmcnt(3) then vmcnt(0). Raw s_barrier (no implicit drain).
// Swizzle: linear LDS dst + pre-swizzled global src + swizzled ds_read.
// EPI: 0 = fp32 store; 1 = bf16 store; 2 = kv-split (n<2048 bf16 Cp, n>=2048
// transposed bf16 Ct). C = (acc + bias[n]) * scale.
template <int EPI>
__global__ __launch_bounds__(512, 4) void gemmp(
    const unsigned short* __restrict__ A0, const unsigned short* __restrict__ A1,
    const unsigned short* __restrict__ A2, int lda,
    const unsigned short* __restrict__ B0, const unsigned short* __restrict__ B1,
    const unsigned short* __restrict__ B2, int ldb,
    void* __restrict__ Cp, int ldc, unsigned short* __restrict__ Ct, int ldt,
    const float* __restrict__ bias, float scale, int Kseg, int nseg) {

    constexpr int ABYTES = 128 * 64;         // A slot part: 128 x 32 bf16
    constexpr int BBYTES = 256 * 64;         // B slot part: 256 x 32 bf16
    constexpr int SLOT = ABYTES + BBYTES;    // 24 KB
    __shared__ __attribute__((aligned(16))) char lds[3 * SLOT];   // 72 KB

    const int tid = threadIdx.x;
    const int gx = gridDim.x;
    const int nwg = gx * gridDim.y;
    int bid = blockIdx.y * gx + blockIdx.x;
    bid = (bid & 7) * (nwg >> 3) + (bid >> 3);    // XCD swizzle (nwg % 8 == 0)
    const int n0 = (bid % gx) * 256;
    const int m0 = (bid / gx) * 128;

    const int lane = tid & 63;
    const int wave = tid >> 6;
    const int wr = wave >> 2, wc = wave & 3;      // 2M x 4N wave grid
    const int ln = lane & 15, quad = lane >> 4;

    const int tps = Kseg >> 5;                    // K=32 slots per segment
    const int NS = tps * nseg;

    // ---- loop-invariant addressing ----
    // staging: global element offsets for the pre-swizzled sources
    const int Pa = swz(tid * 16);
    const int aro = (Pa >> 6) * lda + ((Pa & 63) >> 1);
    int bro[2];
#pragma unroll
    for (int ii = 0; ii < 2; ++ii) {
        const int P = swz(ii * 8192 + tid * 16);
        bro[ii] = (P >> 6) * ldb + ((P & 63) >> 1);
    }
    // ds_read: swizzled byte offsets (within A / B slot regions)
    int aoff[4], boff[4];
#pragma unroll
    for (int i = 0; i < 4; ++i)
        aoff[i] = swz((wr * 64 + i * 16 + ln) * 64 + quad * 16);
#pragma unroll
    for (int j = 0; j < 4; ++j)
        boff[j] = swz((wc * 64 + j * 16 + ln) * 64 + quad * 16);

    auto stage = [&](int s, int r) {
        const int seg = s / tps;
        const int kk = (s - seg * tps) * 32;
        const unsigned short* Ap = seg == 0 ? A0 : (seg == 1 ? A1 : A2);
        const unsigned short* Bp = seg == 0 ? B0 : (seg == 1 ? B1 : B2);
        char* dst = &lds[r * SLOT];
        cp16(Ap + (long)m0 * lda + kk + aro, dst + tid * 16);
        cp16(Bp + (long)n0 * ldb + kk + bro[0], dst + ABYTES + tid * 16);
        cp16(Bp + (long)n0 * ldb + kk + bro[1], dst + ABYTES + 8192 + tid * 16);
    };

    f32x4 acc[4][4] = {};

    // prologue: slots 0,1 staged (6 loads in flight); loop opens with vmcnt(6)
    stage(0, 0);
    stage(1, 1);

    int rc = 0;                                   // ring index of compute slot
    for (int sl = 0; sl < NS; ++sl) {
        if (sl + 2 < NS) {
            int rt = rc + 2; if (rt >= 3) rt -= 3;
            stage(sl + 2, rt);
            asm volatile("s_waitcnt vmcnt(6)" ::: "memory");
        } else if (sl + 1 < NS) {
            asm volatile("s_waitcnt vmcnt(3)" ::: "memory");
        } else {
            asm volatile("s_waitcnt vmcnt(0)" ::: "memory");
        }
        __builtin_amdgcn_s_barrier();             // slot sl visible to all

        const char* base = &lds[rc * SLOT];
        bf16x8 afr[4], bfr[4];
#pragma unroll
        for (int i = 0; i < 4; ++i)
            afr[i] = *(const bf16x8*)(base + aoff[i]);
#pragma unroll
        for (int j = 0; j < 4; ++j)
            bfr[j] = *(const bf16x8*)(base + ABYTES + boff[j]);

        __builtin_amdgcn_s_setprio(1);
#pragma unroll
        for (int i = 0; i < 4; ++i)
#pragma unroll
            for (int j = 0; j < 4; ++j)
                acc[i][j] = __builtin_amdgcn_mfma_f32_16x16x32_bf16(
                    afr[i], bfr[j], acc[i][j], 0, 0, 0);
        __builtin_amdgcn_s_setprio(0);

        asm volatile("s_waitcnt lgkmcnt(0)" ::: "memory");  // reads done (WAR)
        __builtin_amdgcn_s_barrier();
        if (++rc == 3) rc = 0;
    }

    // ---- epilogue: C/D layout col=lane&15, row=quad*4+reg ----
#pragma unroll
    for (int i = 0; i < 4; ++i) {
        const int gm = m0 + wr * 64 + i * 16 + quad * 4;     // rows gm..gm+3
#pragma unroll
        for (int j = 0; j < 4; ++j) {
            const int gn = n0 + wc * 64 + j * 16 + ln;
            const float bv = bias ? bias[gn] : 0.0f;
            const f32x4 d = acc[i][j];
            if (EPI == 2 && gn >= 2048) {
                const int bt = gm >> 12;
                const int rl = gm & 4095;
                ushort4 t4;
                t4.x = f2bf((d[0] + bv) * scale);
                t4.y = f2bf((d[1] + bv) * scale);
                t4.z = f2bf((d[2] + bv) * scale);
                t4.w = f2bf((d[3] + bv) * scale);
                *(ushort4*)&Ct[((long)bt * 2048 + (gn - 2048)) * ldt + rl] = t4;
            } else if (EPI == 0) {
                float* Cf = (float*)Cp;
#pragma unroll
                for (int r = 0; r < 4; ++r)
                    Cf[(long)(gm + r) * ldc + gn] = (d[r] + bv) * scale;
            } else {
                unsigned short* Cb = (unsigned short*)Cp;
#pragma unroll
                for (int r = 0; r < 4; ++r)
                    Cb[(long)(gm + r) * ldc + gn] = f2bf((d[r] + bv) * scale);
            }
        }
    }
}

// ---------- RoPE in-place on bf16 (TOK x ld), ld cols = 16 heads x 128 ----------
__global__ __launch_bounds__(256) void rope_kernel(__hip_bfloat16* __restrict__ p, int ld) {
    const long idx = (long)blockIdx.x * 256 + threadIdx.x;  // < TOK*1024
    const int m = (int)(idx >> 10);
    const int r = (int)(idx & 1023);
    const int h = r >> 6;
    const int i = r & 63;
    const int s = m & (SDIM - 1);
    const float f = (float)s * expf(-(float)i * 0.14391156831212787f);
    float cs, sn;
    sincosf(f, &sn, &cs);
    __hip_bfloat16* b = p + (long)m * ld + h * 128 + i;
    const float x1 = __bfloat162float(b[0]);
    const float x2 = __bfloat162float(b[64]);
    b[0]  = __float2bfloat16(x1 * cs - x2 * sn);
    b[64] = __float2bfloat16(x2 * cs + x1 * sn);
}

// ---------- row softmax over 4096: read fp32, write bf16 in place ----------
__global__ __launch_bounds__(256) void softmax_kernel(float* __restrict__ S) {
    const long row = blockIdx.x;
    float* p = S + row * 4096;
    const int tid = threadIdx.x;
    const int lane = tid & 63;
    const int w = tid >> 6;
    __shared__ float red[4];

    float x[16];
#pragma unroll
    for (int i = 0; i < 4; ++i) {
        const float4 v = reinterpret_cast<const float4*>(p)[i * 256 + tid];
        x[i * 4 + 0] = v.x; x[i * 4 + 1] = v.y; x[i * 4 + 2] = v.z; x[i * 4 + 3] = v.w;
    }
    float m = -1e30f;
#pragma unroll
    for (int i = 0; i < 16; ++i) m = fmaxf(m, x[i]);
#pragma unroll
    for (int off = 1; off < 64; off <<= 1) m = fmaxf(m, __shfl_xor(m, off));
    if (lane == 0) red[w] = m;
    __syncthreads();
    const float M = fmaxf(fmaxf(red[0], red[1]), fmaxf(red[2], red[3]));
    __syncthreads();

    float s = 0.0f;
#pragma unroll
    for (int i = 0; i < 16; ++i) { x[i] = __expf(x[i] - M); s += x[i]; }
#pragma unroll
    for (int off = 1; off < 64; off <<= 1) s += __shfl_xor(s, off);
    if (lane == 0) red[w] = s;
    __syncthreads();                 // all reads done before in-place bf16 write
    const float inv = 1.0f / (red[0] + red[1] + red[2] + red[3]);

    ushort4* dst = (ushort4*)p;      // bf16 packed into first half of the row
#pragma unroll
    for (int i = 0; i < 4; ++i) {
        ushort4 t;
        t.x = f2bf(x[i * 4 + 0] * inv); t.y = f2bf(x[i * 4 + 1] * inv);
        t.z = f2bf(x[i * 4 + 2] * inv); t.w = f2bf(x[i * 4 + 3] * inv);
        dst[i * 256 + tid] = t;
    }
}

extern "C" void kernel_launch(void* const* d_in, const int* in_sizes, int n_in,
                              void* d_out, int out_size, void* d_ws, size_t ws_size,
                              hipStream_t stream) {
    const float* x    = (const float*)d_in[0];
    const float* q_w  = (const float*)d_in[1];
    const float* q_b  = (const float*)d_in[2];
    const float* kv_w = (const float*)d_in[3];
    const float* kv_b = (const float*)d_in[4];
    const float* o_w  = (const float*)d_in[5];
    float* out = (float*)d_out;

    // ws (112 MiB, proven mapped), time-multiplexed:
    //   [0..32M)   qo slot: phase A = kv_w hi/lo split; phase B+ = q / o bf16
    //   [32..64M)  kb slot: K bf16; after last scores reused for o_w hi/lo
    //   [64..96M)  vT bf16 [2 x 2048 x 4096]
    //   [96..112M) q_w hi/lo split
    // d_out (64 MiB) triple-duty:
    //   phase 1: xh|xl bf16 hi/lo split of x
    //   phase 2: per-batch fp32 scores [4096 x 4096], softmax in place
    //   phase 3: final fp32 output (fully overwritten)
    unsigned short* qo  = (unsigned short*)d_ws;
    unsigned short* kb  = qo + (long)TOK * EDIM;
    unsigned short* vT  = kb + (long)TOK * EDIM;
    unsigned short* qwh = vT + (long)BDIM * EDIM * SDIM;
    unsigned short* qwl = qwh + (long)EDIM * EDIM;
    unsigned short* kvh = qo;
    unsigned short* kvl = kvh + (long)2 * EDIM * EDIM;
    unsigned short* owh = kb;
    unsigned short* owl = owh + (long)EDIM * EDIM;
    unsigned short* xh  = (unsigned short*)d_out;
    unsigned short* xl  = xh + (long)TOK * EDIM;
    const unsigned short* nil = nullptr;

    // 0) one-time hi/lo splits
    split_kernel<<<(long)TOK * EDIM / 2048, 256, 0, stream>>>(x, xh, xl);
    split_kernel<<<(long)2 * EDIM * EDIM / 2048, 256, 0, stream>>>(kv_w, kvh, kvl);

    // 1) kv = x @ kv_w^T + kv_b (3 segments: Ah*Bh, Ah*Bl, Al*Bh)
    gemmp<2><<<dim3(16, 64), 512, 0, stream>>>(
        xh, xh, xl, EDIM, kvh, kvl, kvh, EDIM,
        kb, EDIM, vT, SDIM, kv_b, 1.0f, EDIM, 3);

    // 2) q = (x @ q_w^T + q_b) * scale
    split_kernel<<<(long)EDIM * EDIM / 2048, 256, 0, stream>>>(q_w, qwh, qwl);
    gemmp<1><<<dim3(8, 64), 512, 0, stream>>>(
        xh, xh, xl, EDIM, qwh, qwl, qwh, EDIM,
        qo, EDIM, nullptr, 0, q_b, QK_SCALE, EDIM, 3);

    // 3) RoPE on q and k
    rope_kernel<<<(long)TOK * 1024 / 256, 256, 0, stream>>>((__hip_bfloat16*)qo, EDIM);
    rope_kernel<<<(long)TOK * 1024 / 256, 256, 0, stream>>>((__hip_bfloat16*)kb, EDIM);

    // 4) per-batch attention
    for (int b = 0; b < BDIM; ++b) {
        float* scb = (float*)d_out;                    // 4096 x 4096 fp32
        const long ro = (long)b * SDIM * EDIM;

        // scores = q_b @ k_b^T  (512 wgs)
        gemmp<0><<<dim3(16, 32), 512, 0, stream>>>(
            qo + ro, nil, nil, EDIM, kb + ro, nil, nil, EDIM,
            scb, SDIM, nullptr, 0, nullptr, 1.0f, EDIM, 1);

        softmax_kernel<<<SDIM, 256, 0, stream>>>(scb);

        // o_b = P @ (VT)^T  (256 wgs, full chip)
        gemmp<1><<<dim3(8, 32), 512, 0, stream>>>(
            (const unsigned short*)scb, nil, nil, 2 * SDIM,
            vT + b * (long)EDIM * SDIM, nil, nil, SDIM,
            qo + ro, EDIM, nullptr, 0, nullptr, 1.0f, SDIM, 1);
    }

    // 5) out = o @ o_w^T (2 segments: A*Bh, A*Bl); kb slot dead -> o_w split
    split_kernel<<<(long)EDIM * EDIM / 2048, 256, 0, stream>>>(o_w, owh, owl);
    gemmp<0><<<dim3(8, 64), 512, 0, stream>>>(
        qo, qo, nil, EDIM, owh, owl, nil, EDIM,
        out, EDIM, nullptr, 0, nullptr, 1.0f, EDIM, 2);
}

// Round 6
// 1337.178 us; speedup vs baseline: 2.1003x; 2.1003x over previous
//
#include <hip/hip_runtime.h>
#include <hip/hip_bf16.h>

#define BDIM 2
#define SDIM 4096
#define EDIM 2048
#define TOK (BDIM * SDIM)       // 8192
#define QK_SCALE 0.08838834764831845f  // 128^-0.5

typedef short bf16x8 __attribute__((ext_vector_type(8)));
typedef float f32x4 __attribute__((ext_vector_type(4)));

__device__ __forceinline__ unsigned short f2bf(float f) {
    unsigned u = __float_as_uint(f);
    u += 0x7FFF + ((u >> 16) & 1);          // RNE; inputs finite
    return (unsigned short)(u >> 16);
}

// fp32x8 -> bf16 hi + bf16 lo (residual), for near-fp32 MFMA via 3-term split
__device__ __forceinline__ void cvt_split8(const float4 a, const float4 b,
                                           bf16x8& hi, bf16x8& lo) {
    float f[8] = {a.x, a.y, a.z, a.w, b.x, b.y, b.z, b.w};
#pragma unroll
    for (int i = 0; i < 8; ++i) {
        const unsigned short h = f2bf(f[i]);
        hi[i] = (short)h;
        const float hf = __uint_as_float(((unsigned)h) << 16);
        lo[i] = (short)f2bf(f[i] - hf);
    }
}

// async 16B global -> LDS (wave-uniform base + lane*16 dest; per-lane source ok)
__device__ __forceinline__ void cp16(const void* g, void* l) {
    __builtin_amdgcn_global_load_lds(
        (const __attribute__((address_space(1))) unsigned int*)g,
        (__attribute__((address_space(3))) unsigned int*)l, 16, 0, 0);
}

// LDS anti-bank-conflict involution on 64B rows (XOR row bits[3:1] -> byte
// bits[6:4]); 16B-granularity-preserving, self-inverse. Proven bit-correct
// with SQ_LDS_BANK_CONFLICT -> 0 in rounds 4/5. Applied as: linear LDS dst +
// pre-swizzled global source (staging) + swizzled ds_read offsets (reads).
__device__ __forceinline__ int swz(int L) { return L ^ (((L >> 7) & 7) << 4); }

// ---- one-time fp32 -> bf16 hi/lo split (hoisted out of the GEMMs) ----
__global__ __launch_bounds__(256) void split_kernel(
    const float* __restrict__ x,
    unsigned short* __restrict__ xh, unsigned short* __restrict__ xl) {
    const long i = ((long)blockIdx.x * 256 + threadIdx.x) * 8;
    const float4 f0 = *(const float4*)(x + i);
    const float4 f1 = *(const float4*)(x + i + 4);
    bf16x8 hi, lo;
    cvt_split8(f0, f1, hi, lo);
    *(bf16x8*)(xh + i) = hi;
    *(bf16x8*)(xl + i) = lo;
}

// ---------------- MFMA GEMM: C[m,n] = sum_k A[m,k] * B^T[n,k] ----------------
// A: M x K row-major, B: N x K row-major (B^T form). 128x128 tile, BK=32,
// 256 threads = 4 waves (2x2 of 64x64), mfma_f32_16x16x32_bf16.
// SA/SB: 0 = operand is bf16 in global (cp16 direct);
//        2 = operand pre-split: Xp = hi bf16, X2p = lo bf16, both cp16-staged.
//        Product uses Ah*Bh + Ah*Bl + Al*Bh (near-fp32 precision).
// LDS tiles are 128x32 bf16 (64B rows), bank-conflict-free via swz() on both
// the staging source and the fragment ds_reads (values in registers are
// bit-identical to the unswizzled kernel).
// EPI: 0 = fp32 store to Cp;  1 = bf16 store to Cp;
//      2 = kv-split: n<2048 -> bf16 Cp (ldc), n>=2048 -> transposed bf16 Ct:
//          Ct[(batch*2048 + n-2048)*ldt + row_in_batch], batch = row>>12.
// C = (acc + bias[n]) * scale (bias fp32, nullable).
template <int SA, int SB, int EPI>
__global__ __launch_bounds__(256) void mfma_gemm(
    const void* __restrict__ Ap, const void* __restrict__ A2p, int lda,
    const void* __restrict__ Bp, const void* __restrict__ B2p, int ldb,
    void* __restrict__ Cp, int ldc,
    unsigned short* __restrict__ Ct, int ldt,
    const float* __restrict__ bias, float scale, int K) {

    __shared__ __attribute__((aligned(16))) short As[(SA ? 2 : 1) * 128 * 32];
    __shared__ __attribute__((aligned(16))) short Bs[(SB ? 2 : 1) * 128 * 32];

    const int tid = threadIdx.x;
    const int m0 = blockIdx.y * 128;
    const int n0 = blockIdx.x * 128;

    const int lane = tid & 63;
    const int wave = tid >> 6;
    const int ln = lane & 15;
    const int quad = lane >> 4;
    const int wm = (wave >> 1) * 64;
    const int wn = (wave & 1) * 64;

    f32x4 acc[4][4] = {};

    // ---- loop-invariant swizzled addressing ----
    // staging: thread's linear LDS byte slot is p*4096 + tid*16 within the
    // 8KB tile; the global source reads the chunk that belongs there.
    int srow_s[2], scol_s[2];
#pragma unroll
    for (int p = 0; p < 2; ++p) {
        const int P = swz(p * 4096 + tid * 16);
        srow_s[p] = P >> 6;              // tile row 0..127
        scol_s[p] = (P & 63) >> 1;       // element col 0..31
    }
    // fragment ds_reads: swizzled byte offsets
    int aoffb[4], boffb[4];
#pragma unroll
    for (int t = 0; t < 4; ++t) {
        aoffb[t] = swz((wm + t * 16 + ln) * 64 + quad * 16);
        boffb[t] = swz((wn + t * 16 + ln) * 64 + quad * 16);
    }

    for (int kt = 0; kt < K; kt += 32) {
        if (kt) __syncthreads();

        // ---- stage A tile (128x32 bf16 [+lo]) ----
#pragma unroll
        for (int p = 0; p < 2; ++p) {
            const long off = (long)(m0 + srow_s[p]) * lda + kt + scol_s[p];
            char* d = (char*)As + p * 4096 + tid * 16;
            cp16((const unsigned short*)Ap + off, d);
            if (SA == 2) cp16((const unsigned short*)A2p + off, d + 8192);
        }
        // ---- stage B tile (128x32 bf16 [+lo], B^T rows) ----
#pragma unroll
        for (int p = 0; p < 2; ++p) {
            const long off = (long)(n0 + srow_s[p]) * ldb + kt + scol_s[p];
            char* d = (char*)Bs + p * 4096 + tid * 16;
            cp16((const unsigned short*)Bp + off, d);
            if (SB == 2) cp16((const unsigned short*)B2p + off, d + 8192);
        }
        __syncthreads();   // drains vmcnt (global_load_lds)

        // ---- fragments + MFMA ----
        bf16x8 ah[4], bh[4];
#pragma unroll
        for (int t = 0; t < 4; ++t)
            ah[t] = *(const bf16x8*)((const char*)As + aoffb[t]);
#pragma unroll
        for (int t = 0; t < 4; ++t)
            bh[t] = *(const bf16x8*)((const char*)Bs + boffb[t]);

#pragma unroll
        for (int i = 0; i < 4; ++i)
#pragma unroll
            for (int j = 0; j < 4; ++j)
                acc[i][j] = __builtin_amdgcn_mfma_f32_16x16x32_bf16(
                    ah[i], bh[j], acc[i][j], 0, 0, 0);

        if (SB) {
            bf16x8 bl[4];
#pragma unroll
            for (int t = 0; t < 4; ++t)
                bl[t] = *(const bf16x8*)((const char*)Bs + 8192 + boffb[t]);
#pragma unroll
            for (int i = 0; i < 4; ++i)
#pragma unroll
                for (int j = 0; j < 4; ++j)
                    acc[i][j] = __builtin_amdgcn_mfma_f32_16x16x32_bf16(
                        ah[i], bl[j], acc[i][j], 0, 0, 0);
        }
        if (SA) {
            bf16x8 al[4];
#pragma unroll
            for (int t = 0; t < 4; ++t)
                al[t] = *(const bf16x8*)((const char*)As + 8192 + aoffb[t]);
#pragma unroll
            for (int i = 0; i < 4; ++i)
#pragma unroll
                for (int j = 0; j < 4; ++j)
                    acc[i][j] = __builtin_amdgcn_mfma_f32_16x16x32_bf16(
                        al[i], bh[j], acc[i][j], 0, 0, 0);
        }
    }

    // ---- epilogue: C/D layout col=lane&15, row=quad*4+reg ----
#pragma unroll
    for (int i = 0; i < 4; ++i) {
        const int gm = m0 + wm + i * 16 + quad * 4;      // rows gm..gm+3
#pragma unroll
        for (int j = 0; j < 4; ++j) {
            const int gn = n0 + wn + j * 16 + ln;
            const float bv = bias ? bias[gn] : 0.0f;
            const f32x4 d = acc[i][j];
            if (EPI == 2 && gn >= 2048) {
                const int bt = gm >> 12;
                const int rl = gm & 4095;
                ushort4 t4;
                t4.x = f2bf((d[0] + bv) * scale);
                t4.y = f2bf((d[1] + bv) * scale);
                t4.z = f2bf((d[2] + bv) * scale);
                t4.w = f2bf((d[3] + bv) * scale);
                *(ushort4*)&Ct[((long)bt * 2048 + (gn - 2048)) * ldt + rl] = t4;
            } else if (EPI == 0) {
                float* Cf = (float*)Cp;
#pragma unroll
                for (int r = 0; r < 4; ++r)
                    Cf[(long)(gm + r) * ldc + gn] = (d[r] + bv) * scale;
            } else {
                unsigned short* Cb = (unsigned short*)Cp;
#pragma unroll
                for (int r = 0; r < 4; ++r)
                    Cb[(long)(gm + r) * ldc + gn] = f2bf((d[r] + bv) * scale);
            }
        }
    }
}

// ---------- fused RoPE in-place on q and k (both TOK x ld bf16) ----------
__global__ __launch_bounds__(256) void rope2_kernel(
    __hip_bfloat16* __restrict__ q, __hip_bfloat16* __restrict__ k, int ld) {
    long idx = (long)blockIdx.x * 256 + threadIdx.x;   // < 2*TOK*1024
    const long half = (long)TOK * 1024;
    __hip_bfloat16* p = (idx < half) ? q : k;          // block-uniform select
    idx &= (half - 1);
    const int m = (int)(idx >> 10);
    const int r = (int)(idx & 1023);
    const int h = r >> 6;
    const int i = r & 63;
    const int s = m & (SDIM - 1);
    const float f = (float)s * expf(-(float)i * 0.14391156831212787f);
    float cs, sn;
    sincosf(f, &sn, &cs);
    __hip_bfloat16* b = p + (long)m * ld + h * 128 + i;
    const float x1 = __bfloat162float(b[0]);
    const float x2 = __bfloat162float(b[64]);
    b[0]  = __float2bfloat16(x1 * cs - x2 * sn);
    b[64] = __float2bfloat16(x2 * cs + x1 * sn);
}

// ---------- row softmax over 4096: read fp32, write bf16 in place ----------
__global__ __launch_bounds__(256) void softmax_kernel(float* __restrict__ S) {
    const long row = blockIdx.x;
    float* p = S + row * 4096;
    const int tid = threadIdx.x;
    const int lane = tid & 63;
    const int w = tid >> 6;
    __shared__ float red[4];

    float x[16];
#pragma unroll
    for (int i = 0; i < 4; ++i) {
        const float4 v = reinterpret_cast<const float4*>(p)[i * 256 + tid];
        x[i * 4 + 0] = v.x; x[i * 4 + 1] = v.y; x[i * 4 + 2] = v.z; x[i * 4 + 3] = v.w;
    }
    float m = -1e30f;
#pragma unroll
    for (int i = 0; i < 16; ++i) m = fmaxf(m, x[i]);
#pragma unroll
    for (int off = 1; off < 64; off <<= 1) m = fmaxf(m, __shfl_xor(m, off));
    if (lane == 0) red[w] = m;
    __syncthreads();
    const float M = fmaxf(fmaxf(red[0], red[1]), fmaxf(red[2], red[3]));
    __syncthreads();

    float s = 0.0f;
#pragma unroll
    for (int i = 0; i < 16; ++i) { x[i] = __expf(x[i] - M); s += x[i]; }
#pragma unroll
    for (int off = 1; off < 64; off <<= 1) s += __shfl_xor(s, off);
    if (lane == 0) red[w] = s;
    __syncthreads();                 // all reads done before in-place bf16 write
    const float inv = 1.0f / (red[0] + red[1] + red[2] + red[3]);

    ushort4* dst = (ushort4*)p;      // bf16 packed into first half of the row
#pragma unroll
    for (int i = 0; i < 4; ++i) {
        ushort4 t;
        t.x = f2bf(x[i * 4 + 0] * inv); t.y = f2bf(x[i * 4 + 1] * inv);
        t.z = f2bf(x[i * 4 + 2] * inv); t.w = f2bf(x[i * 4 + 3] * inv);
        dst[i * 256 + tid] = t;
    }
}

extern "C" void kernel_launch(void* const* d_in, const int* in_sizes, int n_in,
                              void* d_out, int out_size, void* d_ws, size_t ws_size,
                              hipStream_t stream) {
    const float* x    = (const float*)d_in[0];
    const float* q_w  = (const float*)d_in[1];
    const float* q_b  = (const float*)d_in[2];
    const float* kv_w = (const float*)d_in[3];
    const float* kv_b = (const float*)d_in[4];
    const float* o_w  = (const float*)d_in[5];
    float* out = (float*)d_out;

    // ws (112 MiB, proven mapped), time-multiplexed:
    //   [0..32M)   qo slot: phase A = kv_w hi/lo split; phase B+ = q / o bf16
    //   [32..64M)  kb slot: K bf16; after attention reused for o_w hi/lo
    //   [64..96M)  vT bf16 [2 x 2048 x 4096]
    //   [96..112M) q_w hi/lo split
    // d_out (64 MiB) triple-duty:
    //   phase 1: xh|xl bf16 hi/lo split of x
    //   phase 2: per-batch fp32 scores [4096 x 4096], softmax in place
    //   phase 3: final fp32 output (fully overwritten)
    unsigned short* qo  = (unsigned short*)d_ws;
    unsigned short* kb  = qo + (long)TOK * EDIM;
    unsigned short* vT  = kb + (long)TOK * EDIM;
    unsigned short* qwh = vT + (long)BDIM * EDIM * SDIM;
    unsigned short* qwl = qwh + (long)EDIM * EDIM;
    unsigned short* kvh = qo;
    unsigned short* kvl = kvh + (long)2 * EDIM * EDIM;
    unsigned short* owh = kb;
    unsigned short* owl = owh + (long)EDIM * EDIM;
    unsigned short* xh  = (unsigned short*)d_out;
    unsigned short* xl  = xh + (long)TOK * EDIM;
    const unsigned short* nil = nullptr;

    // 0) one-time hi/lo splits
    split_kernel<<<(long)TOK * EDIM / 2048, 256, 0, stream>>>(x, xh, xl);
    split_kernel<<<(long)2 * EDIM * EDIM / 2048, 256, 0, stream>>>(kv_w, kvh, kvl);

    // 1) kv = x @ kv_w^T + kv_b (3 segments: Ah*Bh, Ah*Bl, Al*Bh)
    mfma_gemm<2, 2, 2><<<dim3(2 * EDIM / 128, TOK / 128), 256, 0, stream>>>(
        xh, xl, EDIM, kvh, kvl, EDIM, kb, EDIM, vT, SDIM, kv_b, 1.0f, EDIM);

    // 2) q = (x @ q_w^T + q_b) * scale
    split_kernel<<<(long)EDIM * EDIM / 2048, 256, 0, stream>>>(q_w, qwh, qwl);
    mfma_gemm<2, 2, 1><<<dim3(EDIM / 128, TOK / 128), 256, 0, stream>>>(
        xh, xl, EDIM, qwh, qwl, EDIM, qo, EDIM, nullptr, 0, q_b, QK_SCALE, EDIM);

    // 3) fused RoPE on q and k (one launch)
    rope2_kernel<<<(long)2 * TOK * 1024 / 256, 256, 0, stream>>>(
        (__hip_bfloat16*)qo, (__hip_bfloat16*)kb, EDIM);

    // 4) per-batch attention (full 4096-row score buffer in d_out; xh/xl dead)
    for (int b = 0; b < BDIM; ++b) {
        float* scb = (float*)d_out;                    // 4096 x 4096 fp32
        const long ro = (long)b * SDIM * EDIM;

        // scores = q_b @ k_b^T  (fp32, full batch; 32x32 = 1024 blocks)
        mfma_gemm<0, 0, 0><<<dim3(SDIM / 128, SDIM / 128), 256, 0, stream>>>(
            qo + ro, nil, EDIM, kb + ro, nil, EDIM,
            scb, SDIM, nullptr, 0, nullptr, 1.0f, EDIM);

        // softmax rows: fp32 -> bf16 in place (4096 rows, one launch)
        softmax_kernel<<<SDIM, 256, 0, stream>>>(scb);

        // o_b = P @ (VT)^T  (bf16 into qo rows; 16x32 = 512 blocks)
        mfma_gemm<0, 0, 1><<<dim3(EDIM / 128, SDIM / 128), 256, 0, stream>>>(
            (const unsigned short*)scb, nil, 2 * SDIM,   // P bf16, row stride 8192
            vT + b * (long)EDIM * SDIM, nil, SDIM,
            qo + ro, EDIM, nullptr, 0, nullptr, 1.0f, SDIM);
    }

    // 5) out = o @ o_w^T -> fp32 (overwrites all of d_out; kb slot dead)
    split_kernel<<<(long)EDIM * EDIM / 2048, 256, 0, stream>>>(o_w, owh, owl);
    mfma_gemm<0, 2, 0><<<dim3(EDIM / 128, TOK / 128), 256, 0, stream>>>(
        qo, nil, EDIM, owh, owl, EDIM, out, EDIM, nullptr, 0, nullptr, 1.0f, EDIM);
}